// Round 8
// baseline (237.066 us; speedup 1.0000x reference)
//
#include <hip/hip_runtime.h>

typedef __attribute__((ext_vector_type(4))) int            vi4;
typedef __attribute__((ext_vector_type(4))) float          vf4;
typedef __attribute__((ext_vector_type(8))) short          vs8;
typedef __attribute__((ext_vector_type(2))) unsigned int   vu2;
typedef unsigned short u16;
typedef unsigned int   u32;

#define LOG2E  1.4426950408889634f
#define QSCALE 0.2550484109f   /* (1/sqrt(32)) * log2(e) */

static __device__ __forceinline__ u16 f2bf(float f) {
  u32 u = __builtin_bit_cast(u32, f);
  u32 r = (u + 0x7fffu + ((u >> 16) & 1u)) >> 16;   // RNE
  return (u16)r;
}
static __device__ __forceinline__ float bfu_lo(u32 u) {
  return __builtin_bit_cast(float, u << 16);
}
static __device__ __forceinline__ float bfu_hi(u32 u) {
  return __builtin_bit_cast(float, u & 0xffff0000u);
}
// pack bf16(trunc) of a (lo) and b (hi) in one v_perm_b32
static __device__ __forceinline__ u32 packbf_perm(float a, float b) {
  return __builtin_amdgcn_perm(__builtin_bit_cast(u32, b),
                               __builtin_bit_cast(u32, a), 0x07060302u);
}

// async global->LDS DMA, 16B per lane. LDS dest = wave-uniform base + lane*16.
static __device__ __forceinline__ void ldsdma16(void* lds, const void* g) {
  __builtin_amdgcn_global_load_lds(
      (const u32 __attribute__((address_space(1)))*)g,
      (u32 __attribute__((address_space(3)))*)lds, 16, 0, 0);
}

// ---------------- fused prep ----------------
// grid: [0,8192) cvt x | [8192,8960) Wqkv^T | [8960,9216) Wout^T | [9216,9728) bias
// Bias bf16-packed in S^T MFMA C-fragment order:
//   u32 idx = h*524288 + (qt*16+t)*4096 + tid*16 + (ti*4+tj)*2 + p
//   pair p: r=2p (lo16), r=2p+1 (hi16); m = l15, j = tj*16+quad*4+r, values *log2e
__global__ void prep_all(const float* __restrict__ x, u16* __restrict__ xbf,
                         const float* __restrict__ Wqkv, u16* __restrict__ WqkvT,
                         const float* __restrict__ Wout, u16* __restrict__ WoutT,
                         const int* __restrict__ rel, const float* __restrict__ table,
                         u32* __restrict__ bias_pk) {
  __shared__ __align__(8) u16 relS[64 * 32];
  int bid = blockIdx.x, tid = threadIdx.x;
  if (bid < 8192) {
    int i = (bid * 256 + tid) * 4;
    vf4 v = *(const vf4*)&x[i];
    u32 lo = (u32)f2bf(v[0]) | ((u32)f2bf(v[1]) << 16);
    u32 hi = (u32)f2bf(v[2]) | ((u32)f2bf(v[3]) << 16);
    vu2 o; o[0] = lo; o[1] = hi;
    *(vu2*)&xbf[i] = o;
  } else if (bid < 9216) {
    const float* src; u16* dst; int C, idx;
    if (bid < 8960) { src = Wqkv; dst = WqkvT; C = 768; idx = (bid - 8192) * 256 + tid; }
    else            { src = Wout; dst = WoutT; C = 256; idx = (bid - 8960) * 256 + tid; }
    int r = idx / C, c = idx - r * C;
    dst[c * 256 + r] = f2bf(src[idx]);
  } else {
    int b2 = bid - 9216;                       // 0..511
    int qt = b2 >> 6, t = (b2 >> 2) & 15, s = b2 & 3;
    int ti = s >> 1, jhalf = s & 1;
    int wave = tid >> 6, quad = (tid >> 4) & 3, l15 = tid & 15;
    int jbase = t * 64 + jhalf * 32;

    // phase 1: coalesced rel tile -> LDS (u16)
#pragma unroll
    for (int p = 0; p < 2; ++p) {
      int task = p * 256 + tid;
      int q = task >> 3, unit = task & 7;
      int m = qt * 128 + (q >> 4) * 32 + ti * 16 + (q & 15);
      vi4 v = *(const vi4*)&rel[m * 1024 + jbase + unit * 4];
      vu2 pk;
      pk[0] = (u32)(v[0] & 0xffff) | ((u32)v[1] << 16);
      pk[1] = (u32)(v[2] & 0xffff) | ((u32)v[3] << 16);
      *(vu2*)&relS[q * 32 + unit * 4] = pk;
    }
    __syncthreads();

    // phase 2: gather table, emit bf16 fragments
    int mrow = wave * 16 + l15;
    float vals[8][8];
#pragma unroll
    for (int tjl = 0; tjl < 2; ++tjl)
#pragma unroll
      for (int r = 0; r < 4; ++r) {
        int idx = relS[mrow * 32 + tjl * 16 + quad * 4 + r];
        vf4 a = *(const vf4*)&table[idx * 8];
        vf4 bb = *(const vf4*)&table[idx * 8 + 4];
#pragma unroll
        for (int h = 0; h < 4; ++h) {
          vals[tjl * 4 + r][h] = a[h];
          vals[tjl * 4 + r][h + 4] = bb[h];
        }
      }
#pragma unroll
    for (int h = 0; h < 8; ++h) {
      u32 o[4];
#pragma unroll
      for (int tjl = 0; tjl < 2; ++tjl)
#pragma unroll
        for (int p = 0; p < 2; ++p) {
          u32 lo = f2bf(vals[tjl * 4 + 2 * p][h] * LOG2E);
          u32 hi = f2bf(vals[tjl * 4 + 2 * p + 1][h] * LOG2E);
          o[tjl * 2 + p] = lo | (hi << 16);
        }
      *(vi4*)&bias_pk[h * 524288 + (qt * 16 + t) * 4096 + tid * 16 + s * 4] =
          *(const vi4*)o;
    }
  }
}

// ---------------- GEMM: C[M x NC] = A[M x 256] * Bt[NC x 256]^T ----------------
template <int EPI>
__global__ __launch_bounds__(256, 2) void gemm_k256(
    const u16* __restrict__ A, const u16* __restrict__ Bt,
    u16* __restrict__ q_out, u16* __restrict__ k_out, u16* __restrict__ v_out,
    float* __restrict__ c_out, const float* __restrict__ bias) {
  __shared__ __align__(16) u16 SMEM[EPI == 0 ? 128 * 136 : 8192];
  u16* As = SMEM;
  u16* Bs = SMEM + 4096;
  const int tid = threadIdx.x;
  const int lane15 = tid & 15, quad = (tid >> 4) & 3, wave = tid >> 6;
  const int wr = (wave & 1) * 64, wc = (wave >> 1) * 64;
  const int m0 = blockIdx.y * 128, n0 = blockIdx.x * 128;

  const u16* Ag = &A[(m0 + (tid >> 2)) * 256 + (tid & 3) * 8];
  const u16* Bg = &Bt[(n0 + (tid >> 2)) * 256 + (tid & 3) * 8];
  u16* AsW = &As[wave * 512];
  u16* BsW = &Bs[wave * 512];

  const vf4 z4 = {0.f, 0.f, 0.f, 0.f};
  vf4 acc[4][4];
#pragma unroll
  for (int i = 0; i < 4; ++i)
#pragma unroll
    for (int j = 0; j < 4; ++j) acc[i][j] = z4;

  for (int k0 = 0; k0 < 256; k0 += 32) {
    __syncthreads();
    ldsdma16(AsW,        Ag + k0);
    ldsdma16(AsW + 2048, Ag + k0 + 64 * 256);
    ldsdma16(BsW,        Bg + k0);
    ldsdma16(BsW + 2048, Bg + k0 + 64 * 256);
    __syncthreads();
    vs8 af[4], bfr[4];
#pragma unroll
    for (int ti = 0; ti < 4; ++ti)
      af[ti] = *(const vs8*)&As[(wr + ti * 16 + lane15) * 32 + quad * 8];
#pragma unroll
    for (int tj = 0; tj < 4; ++tj)
      bfr[tj] = *(const vs8*)&Bs[(wc + tj * 16 + lane15) * 32 + quad * 8];
#pragma unroll
    for (int ti = 0; ti < 4; ++ti)
#pragma unroll
      for (int tj = 0; tj < 4; ++tj)
        acc[ti][tj] = __builtin_amdgcn_mfma_f32_16x16x32_bf16(af[ti], bfr[tj],
                                                              acc[ti][tj], 0, 0, 0);
  }

  if (EPI == 0) {
    const int which = n0 >> 8;
    const int bb = m0 >> 10, nn0 = m0 & 1023;
    u16* Cs = SMEM;                               // [128][136]
    __syncthreads();
    if (which < 2) {
      float sc = (which == 0) ? QSCALE : 1.f;
#pragma unroll
      for (int tj = 0; tj < 4; ++tj) {
        int col = wc + tj * 16 + lane15;
#pragma unroll
        for (int ti = 0; ti < 4; ++ti) {
          int row0 = wr + ti * 16 + quad * 4;
#pragma unroll
          for (int r = 0; r < 4; ++r)
            Cs[(row0 + r) * 136 + col] = f2bf(acc[ti][tj][r] * sc);
        }
      }
      __syncthreads();
      u16* base = (which == 0) ? q_out : k_out;
#pragma unroll
      for (int hp = 0; hp < 4; ++hp) {
        int hh = ((n0 + hp * 32) >> 5) & 7;
        u16* pb = base + ((bb * 8 + hh) * 1024 + nn0) * 32;
#pragma unroll
        for (int p2 = 0; p2 < 2; ++p2) {
          int task = p2 * 256 + tid;
          int row = task >> 2, unit = task & 3;
          vi4 v = *(const vi4*)&Cs[row * 136 + hp * 32 + unit * 8];
          *(vi4*)&pb[row * 32 + unit * 8] = v;
        }
      }
    } else {
#pragma unroll
      for (int tj = 0; tj < 4; ++tj) {
        int col = wc + tj * 16 + lane15;
#pragma unroll
        for (int ti = 0; ti < 4; ++ti) {
          int row0 = wr + ti * 16 + quad * 4;
          vu2 pk;
          pk[0] = (u32)f2bf(acc[ti][tj][0]) | ((u32)f2bf(acc[ti][tj][1]) << 16);
          pk[1] = (u32)f2bf(acc[ti][tj][2]) | ((u32)f2bf(acc[ti][tj][3]) << 16);
          *(vu2*)&Cs[col * 136 + row0] = pk;
        }
      }
      __syncthreads();
#pragma unroll
      for (int p = 0; p < 8; ++p) {
        int task = p * 256 + tid;
        int col = task >> 4, unit = task & 15;
        int cg = n0 + col;
        int hh = (cg >> 5) & 7, d = cg & 31;
        vi4 v = *(const vi4*)&Cs[col * 136 + unit * 8];
        *(vi4*)&v_out[((bb * 8 + hh) * 32 + d) * 1024 + nn0 + unit * 8] = v;
      }
    }
  } else {
#pragma unroll
    for (int tj = 0; tj < 4; ++tj) {
      int colg = n0 + wc + tj * 16 + lane15;
      float bo = bias[colg];
#pragma unroll
      for (int ti = 0; ti < 4; ++ti)
#pragma unroll
        for (int r = 0; r < 4; ++r) {
          int rowg = m0 + wr + ti * 16 + quad * 4 + r;
          c_out[rowg * 256 + colg] = acc[ti][tj][r] + bo;
        }
    }
  }
}

// ---------------- flash attention (S^T, x2-unrolled, immediate LDS offsets) ----
// LDS u16 index map: Ks[2] @ 0 / 2560; Vt[2] @ 5120 / 7424; Ps @ 9728 + wave*2304
#define MFMA_BF16 __builtin_amdgcn_mfma_f32_16x16x32_bf16

#define QK_TILE(AF, PTOFF, U0, U1)                                         \
  {                                                                        \
    vf4 c; c[0] = bfu_lo(U0); c[1] = bfu_hi(U0);                           \
    c[2] = bfu_lo(U1); c[3] = bfu_hi(U1);                                  \
    vf4 st = MFMA_BF16(bk[_tj], AF, c, 0, 0, 0);                           \
    float p0 = __builtin_exp2f(st[0]);                                     \
    float p1 = __builtin_exp2f(st[1]);                                     \
    float p2 = __builtin_exp2f(st[2]);                                     \
    float p3 = __builtin_exp2f(st[3]);                                     \
    vu2 pk; pk[0] = packbf_perm(p0, p1); pk[1] = packbf_perm(p2, p3);      \
    *(vu2*)&L[pwb + (PTOFF) + _tj * 16] = pk;                              \
  }

#define FLASH_HALF(T, CUR, NXT, BC0, BC1, BN0, BN1, LAST)                  \
  {                                                                        \
    vi4 b1a = *(const vi4*)(Bpk + (T) * 4096 + 8);                         \
    vi4 b1b = *(const vi4*)(Bpk + (T) * 4096 + 12);                        \
    if (!(LAST)) {                                                         \
      kreg = *(const vi4*)(Kg + ((T) + 1) * 2048);                         \
      vreg = *(const vi4*)(Vg + ((T) + 1) * 64);                           \
      BN0 = *(const vi4*)(Bpk + ((T) + 1) * 4096);                         \
      BN1 = *(const vi4*)(Bpk + ((T) + 1) * 4096 + 4);                     \
    }                                                                      \
    __syncthreads();                                                       \
    vs8 bk[4];                                                             \
    _Pragma("unroll") for (int _tj = 0; _tj < 4; ++_tj)                    \
        bk[_tj] = *(const vs8*)&L[bkb + (CUR) * 2560 + _tj * 640];         \
    _Pragma("unroll") for (int _tj = 0; _tj < 4; ++_tj) {                  \
      u32 u0 = (_tj < 2) ? (u32)BC0[_tj * 2] : (u32)BC1[(_tj - 2) * 2];    \
      u32 u1 = (_tj < 2) ? (u32)BC0[_tj * 2 + 1] : (u32)BC1[(_tj - 2) * 2 + 1]; \
      QK_TILE(af0, 0, u0, u1)                                              \
    }                                                                      \
    _Pragma("unroll") for (int _tj = 0; _tj < 4; ++_tj) {                  \
      u32 u0 = (_tj < 2) ? (u32)b1a[_tj * 2] : (u32)b1b[(_tj - 2) * 2];    \
      u32 u1 = (_tj < 2) ? (u32)b1a[_tj * 2 + 1] : (u32)b1b[(_tj - 2) * 2 + 1]; \
      QK_TILE(af1, 1152, u0, u1)                                           \
    }                                                                      \
    _Pragma("unroll") for (int kk = 0; kk < 2; ++kk) {                     \
      vs8 pf0 = *(const vs8*)&L[pfb + kk * 32];                            \
      vs8 pf1 = *(const vs8*)&L[pfb + 1152 + kk * 32];                     \
      vs8 bv0 = *(const vs8*)&L[bvb + (CUR) * 2304 + kk * 32];             \
      vs8 bv1 = *(const vs8*)&L[bvb + (CUR) * 2304 + 1152 + kk * 32];      \
      O00 = MFMA_BF16(bv0, pf0, O00, 0, 0, 0);                             \
      O01 = MFMA_BF16(bv1, pf0, O01, 0, 0, 0);                             \
      La0 = MFMA_BF16(onesv, pf0, La0, 0, 0, 0);                           \
      O10 = MFMA_BF16(bv0, pf1, O10, 0, 0, 0);                             \
      O11 = MFMA_BF16(bv1, pf1, O11, 0, 0, 0);                             \
      La1 = MFMA_BF16(onesv, pf1, La1, 0, 0, 0);                           \
    }                                                                      \
    if (!(LAST)) {                                                         \
      *(vi4*)&L[ksw + (NXT) * 2560] = kreg;                                \
      *(vi4*)&L[vsw + (NXT) * 2304] = vreg;                                \
    }                                                                      \
  }

__global__ __launch_bounds__(256, 4) void flash_attn(
    const u16* __restrict__ Qws, const u16* __restrict__ Kws,
    const u16* __restrict__ Vtws, const u32* __restrict__ bias_pk,
    u16* __restrict__ Ows) {
  __shared__ __align__(16) u16 L[18944];

  const int tid = threadIdx.x;
  const int l15 = tid & 15, quad = (tid >> 4) & 3, wave = tid >> 6;
  const int bid = blockIdx.x;
  const int h = bid & 7, b = (bid >> 3) & 31, qt = bid >> 8;
  const int q0 = qt * 128;
  const int bh = b * 8 + h;
  const u16* Qbase = Qws + (bh * 1024 + q0) * 32;
  const u16* Kg = Kws + bh * 1024 * 32 + (tid >> 2) * 32 + (tid & 3) * 8;
  const u16* Vg = Vtws + bh * 32 * 1024 + (tid >> 3) * 1024 + (tid & 7) * 8;
  const u32* Bpk = bias_pk + h * 524288 + qt * 65536 + tid * 16;

  // persistent LDS index bases (u16 units), all reads/writes use +imm
  const int ksw = (tid >> 2) * 40 + (tid & 3) * 8;
  const int vsw = 5120 + (tid >> 3) * 72 + (tid & 7) * 8;
  const int bkb = l15 * 40 + quad * 8;
  const int bvb = 5120 + l15 * 72 + quad * 8;
  const int pfb = 9728 + wave * 2304 + l15 * 72 + quad * 8;
  const int pwb = 9728 + wave * 2304 + l15 * 72 + quad * 4;

  // Q fragments straight from global
  vs8 af0 = *(const vs8*)&Qbase[(wave * 32 + l15) * 32 + quad * 8];
  vs8 af1 = *(const vs8*)&Qbase[(wave * 32 + 16 + l15) * 32 + quad * 8];

  // prologue: stage tile 0, prefetch bias t=0 (ti=0 frags)
  vi4 kreg = *(const vi4*)Kg;
  vi4 vreg = *(const vi4*)Vg;
  *(vi4*)&L[ksw] = kreg;
  *(vi4*)&L[vsw] = vreg;
  vi4 bA0 = *(const vi4*)(Bpk);
  vi4 bA1 = *(const vi4*)(Bpk + 4);
  vi4 bB0 = bA0, bB1 = bA1;

  const vf4 z4 = {0.f, 0.f, 0.f, 0.f};
  vf4 O00 = z4, O01 = z4, O10 = z4, O11 = z4;
  vf4 La0 = z4, La1 = z4;

  vs8 onesv;
#pragma unroll
  for (int i = 0; i < 8; ++i) onesv[i] = (short)0x3F80;   // bf16 1.0

  for (int tt = 0; tt < 8; ++tt) {
    const int t0 = tt * 2, t1 = tt * 2 + 1;
    FLASH_HALF(t0, 0, 1, bA0, bA1, bB0, bB1, 0)
    FLASH_HALF(t1, 1, 0, bB0, bB1, bA0, bA1, (tt == 7))
  }

  // epilogue
  {
    float inv0 = __builtin_amdgcn_rcpf(La0[0]);
    float inv1 = __builtin_amdgcn_rcpf(La1[0]);
    int m0 = q0 + wave * 32 + l15;
    int rb0 = (b * 1024 + m0) * 256 + h * 32;
    int rb1 = (b * 1024 + m0 + 16) * 256 + h * 32;
#pragma unroll
    for (int tj2 = 0; tj2 < 2; ++tj2) {
      vu2 pk;
      pk[0] = packbf_perm(O00[0] * inv0, O00[1] * inv0);
      pk[1] = packbf_perm(O00[2] * inv0, O00[3] * inv0);
      vu2 qk;
      const vf4& oo = (tj2 == 0) ? O00 : O01;
      qk[0] = packbf_perm(oo[0] * inv0, oo[1] * inv0);
      qk[1] = packbf_perm(oo[2] * inv0, oo[3] * inv0);
      *(vu2*)&Ows[rb0 + tj2 * 16 + quad * 4] = qk;
      const vf4& o1 = (tj2 == 0) ? O10 : O11;
      vu2 rk;
      rk[0] = packbf_perm(o1[0] * inv1, o1[1] * inv1);
      rk[1] = packbf_perm(o1[2] * inv1, o1[3] * inv1);
      *(vu2*)&Ows[rb1 + tj2 * 16 + quad * 4] = rk;
    }
  }
}

// ---------------- launch ----------------
extern "C" void kernel_launch(void* const* d_in, const int* in_sizes, int n_in,
                              void* d_out, int out_size, void* d_ws, size_t ws_size,
                              hipStream_t stream) {
  (void)in_sizes; (void)n_in; (void)out_size; (void)ws_size;
  const float* x     = (const float*)d_in[0];
  const float* Wqkv  = (const float*)d_in[1];
  const float* table = (const float*)d_in[2];
  const float* Wout  = (const float*)d_in[3];
  const float* bout  = (const float*)d_in[4];
  const int*   rel   = (const int*)d_in[5];
  float* out = (float*)d_out;

  char* ws = (char*)d_ws;
  u16* xbf    = (u16*)(ws);              // bf16 x; later reused as attention O
  u16* Qws    = (u16*)(ws + 16777216);
  u16* Kws    = (u16*)(ws + 33554432);
  u16* Vtws   = (u16*)(ws + 50331648);   // [32][8][32][1024] V^T
  u32* biaspk = (u32*)(ws + 67108864);   // 16.8MB bf16 S^T-fragment bias
  u16* WqkvT  = (u16*)(ws + 83886080);
  u16* WoutT  = (u16*)(ws + 84279296);

  prep_all<<<9728, 256, 0, stream>>>(x, xbf, Wqkv, WqkvT, Wout, WoutT,
                                     rel, table, biaspk);
  gemm_k256<0><<<dim3(6, 256), 256, 0, stream>>>(xbf, WqkvT, Qws, Kws, Vtws,
                                                 nullptr, nullptr);
  flash_attn<<<2048, 256, 0, stream>>>(Qws, Kws, Vtws, biaspk, xbf);
  gemm_k256<1><<<dim3(2, 256), 256, 0, stream>>>(xbf, WoutT,
                                                 nullptr, nullptr, nullptr, out, bout);
}